// Round 7
// baseline (413.868 us; speedup 1.0000x reference)
//
#include <hip/hip_runtime.h>
#include <hip/hip_fp16.h>
#include <math.h>

#define SDE_B 16384
#define SDE_S 16
#define SDE_STEPS 50
#define SDE_L 128
#define SDE_DT 0.02f
#define SDE_SQRT_DT 0.14142135623730951f
#define SDE_TEMP 20.0f
#define LOG2E 1.44269504088896340736f
#define LN2 0.69314718055994530942f
#define CT (SDE_TEMP * LOG2E)       /* hazard arg scale */

#if __has_builtin(__builtin_amdgcn_exp2f)
__device__ __forceinline__ float fexp2(float x) { return __builtin_amdgcn_exp2f(x); }
#else
__device__ __forceinline__ float fexp2(float x) { return __exp2f(x); }
#endif

#if __has_builtin(__builtin_amdgcn_logf)
__device__ __forceinline__ float flog2(float x) { return __builtin_amdgcn_logf(x); }
#else
__device__ __forceinline__ float flog2(float x) { return __log2f(x); }
#endif

#if __has_builtin(__builtin_amdgcn_rcpf)
__device__ __forceinline__ float frcp(float x) { return __builtin_amdgcn_rcpf(x); }
#else
__device__ __forceinline__ float frcp(float x) { return 1.0f / x; }
#endif

#if __has_builtin(__builtin_amdgcn_fmed3f)
__device__ __forceinline__ float fmed3(float x, float lo, float hi) {
    return __builtin_amdgcn_fmed3f(x, lo, hi);
}
#else
__device__ __forceinline__ float fmed3(float x, float lo, float hi) {
    return fminf(fmaxf(x, lo), hi);
}
#endif

// wave-uniform float -> SGPR
__device__ __forceinline__ float uni(float v) {
#if __has_builtin(__builtin_amdgcn_readfirstlane)
    return __int_as_float(__builtin_amdgcn_readfirstlane(__float_as_int(v)));
#else
    return v;
#endif
}

// extract one f16 from a half2 as float; constant `hi` folds; feeding fmaf()
// lets clang form v_fma_mix_f32 (full-rate, no cvt inst).
__device__ __forceinline__ float hsel(__half2 h, int hi) {
    return __half2float(hi ? __high2half(h) : __low2half(h));
}

// stable softplus: max(y,0) + log(1+exp(-|y|))
__device__ __forceinline__ float softplus_fast(float y) {
    float m = fmaxf(y, 0.0f);
    float e = fexp2(-fabsf(y) * LOG2E);
    return fmaf(LN2, flog2(1.0f + e), m);
}

// sum over the 4-lane quad (lanes grouped as sim*4+q) via DPP quad_perm
__device__ __forceinline__ float quad_sum(float v) {
#if __has_builtin(__builtin_amdgcn_mov_dpp)
    int i = __float_as_int(v);
    v += __int_as_float(__builtin_amdgcn_mov_dpp(i, 0xB1, 0xF, 0xF, true)); // xor 1
    i = __float_as_int(v);
    v += __int_as_float(__builtin_amdgcn_mov_dpp(i, 0x4E, 0xF, 0xF, true)); // xor 2
    return v;
#else
    v += __shfl_xor(v, 1, 64);
    v += __shfl_xor(v, 2, 64);
    return v;
#endif
}

__device__ __forceinline__ float fixnum(float v) {
    if (isnan(v)) return 0.0f;
    if (isinf(v)) return v > 0.0f ? 3.4028234663852886e38f : -3.4028234663852886e38f;
    return v;
}

// One wave per batch element b. 64 lanes = 16 sims x 4 hidden-quarters.
// lane = s*4 + q: sim s, hidden units j = 4*i + q, i in [0,16).
// All weights f16-packed (half2) -> 40 VGPRs; total demand ~54 fits the
// 64-VGPR budget (8 waves/SIMD). tanh via Pade [5/4] (R2-R5 validated,
// max err ~1.4e-3 with +-3.8 clamp) - cuts 16 exp/step (transc ~14.5cyc).
// Noise double-buffered one full iteration ahead to hide ~900cyc HBM latency.
__global__ void __launch_bounds__(256) sde_kernel(
    const float* __restrict__ z,  const float* __restrict__ W1,
    const float* __restrict__ b1, const float* __restrict__ W2,
    const float* __restrict__ b2, const float* __restrict__ Wb,
    const float* __restrict__ bb, const float* __restrict__ Wn,
    const float* __restrict__ bn, const float* __restrict__ osc,
    const float* __restrict__ obias, const float* __restrict__ noise,
    float* __restrict__ out)
{
    const int lane = threadIdx.x & 63;
    const int wv = threadIdx.x >> 6;
    const int b = blockIdx.x * 4 + wv;
    const int s = lane >> 2;
    const int q = lane & 3;

    const float* zr = z + (size_t)b * SDE_L;

    // --- setup: lane l computes zW1 entry for hidden unit j = l ---
    float accz = b1[lane];
    {
        const float* wrow = W1 + lane * 130 + 2;
        #pragma unroll
        for (int m = 0; m < SDE_L; m += 2) {
            float2 w = *(const float2*)(wrow + m);
            accz = fmaf(zr[m], w.x, accz);
            accz = fmaf(zr[m + 1], w.y, accz);
        }
    }

    // --- boundary / ndt: 128-dot reduced over the wave ---
    float zb0 = zr[2 * lane], zb1 = zr[2 * lane + 1];
    float pb = fmaf(zb0, Wb[2 * lane], zb1 * Wb[2 * lane + 1]);
    float pn = fmaf(zb0, Wn[2 * lane], zb1 * Wn[2 * lane + 1]);
    #pragma unroll
    for (int off = 32; off > 0; off >>= 1) {
        pb += __shfl_xor(pb, off, 64);
        pn += __shfl_xor(pn, off, 64);
    }
    // wave-uniform scalars -> SGPRs (frees VGPRs; compiler can't prove
    // uniformity of shuffle-reduced values on its own)
    const float Hh = uni(CT * (0.5f * (softplus_fast(pb + bb[0]) + 0.3f)));
    const float ndt = uni(softplus_fast(pn + bn[0]) + 0.05f);

    // --- pack this lane's 16 hidden units (j = 4i+q) as f16 half2 pairs ---
    __half2 zwh[8], wxh[8], wth[8], wah[8], wbh[8];
    #pragma unroll
    for (int p = 0; p < 8; ++p) {
        int j0 = 4 * (2 * p) + q, j1 = 4 * (2 * p + 1) + q;
        float zw0 = __shfl(accz, j0, 64), zw1 = __shfl(accz, j1, 64);
        zwh[p] = __halves2half2(__float2half_rn(zw0), __float2half_rn(zw1));
        float2 wa0 = *(const float2*)(W1 + j0 * 130);  // {w1x, w1t}
        float2 wa1 = *(const float2*)(W1 + j1 * 130);
        wxh[p] = __halves2half2(__float2half_rn(wa0.x), __float2half_rn(wa1.x));
        wth[p] = __halves2half2(__float2half_rn(wa0.y), __float2half_rn(wa1.y));
        wah[p] = __halves2half2(__float2half_rn(W2[j0]), __float2half_rn(W2[j1]));
        wbh[p] = __halves2half2(__float2half_rn(W2[64 + j0]), __float2half_rn(W2[64 + j1]));
    }
    // per-lane accumulator bases: quad-sum over 4 lanes yields b2
    const float a0base = uni(0.25f * b2[0]);
    const float a1base = uni(0.25f * b2[1]);

    // noise addressing: SGPR base (noise, advanced by scalar k*B*S) +
    // 32-bit lane offset -> saddr global_load, no 64-bit VGPR pointer.
    const int noff = b * SDE_S + s;

    float x = 0.0f, surv = 1.0f, ert = 0.0f, ecorr = 0.0f;
    float t = 0.0f;
    float nz_cur = noise[noff];   // k=0 preload

    for (int k = 0; k < SDE_STEPS; ++k) {
        // prefetch k+1 (consumed next iteration, ~full iteration of cover)
        int kn = (k + 1 < SDE_STEPS) ? k + 1 : k;      // scalar, s_cselect
        float nz_nxt = noise[(size_t)kn * (SDE_B * SDE_S) + noff];

        float a0 = a0base, a1 = a1base;
        #pragma unroll
        for (int g = 0; g < 4; ++g) {
            // 4 units: pairs p = 2g (lo,hi), 2g+1 (lo,hi)
            float pr0 = fmaf(x, hsel(wxh[2*g], 0), fmaf(t, hsel(wth[2*g], 0), hsel(zwh[2*g], 0)));
            float pr1 = fmaf(x, hsel(wxh[2*g], 1), fmaf(t, hsel(wth[2*g], 1), hsel(zwh[2*g], 1)));
            float pr2 = fmaf(x, hsel(wxh[2*g+1], 0), fmaf(t, hsel(wth[2*g+1], 0), hsel(zwh[2*g+1], 0)));
            float pr3 = fmaf(x, hsel(wxh[2*g+1], 1), fmaf(t, hsel(wth[2*g+1], 1), hsel(zwh[2*g+1], 1)));
            // Pade [5/4] tanh, input clamped to +-3.8 via med3
            pr0 = fmed3(pr0, -3.8f, 3.8f);
            pr1 = fmed3(pr1, -3.8f, 3.8f);
            pr2 = fmed3(pr2, -3.8f, 3.8f);
            pr3 = fmed3(pr3, -3.8f, 3.8f);
            float t0 = pr0 * pr0, t1 = pr1 * pr1, t2 = pr2 * pr2, t3 = pr3 * pr3;
            float n0 = pr0 * fmaf(t0, t0 + 105.0f, 945.0f);
            float n1 = pr1 * fmaf(t1, t1 + 105.0f, 945.0f);
            float n2 = pr2 * fmaf(t2, t2 + 105.0f, 945.0f);
            float n3 = pr3 * fmaf(t3, t3 + 105.0f, 945.0f);
            float d0 = fmaf(t0, fmaf(t0, 15.0f, 420.0f), 945.0f);
            float d1 = fmaf(t1, fmaf(t1, 15.0f, 420.0f), 945.0f);
            float d2 = fmaf(t2, fmaf(t2, 15.0f, 420.0f), 945.0f);
            float d3 = fmaf(t3, fmaf(t3, 15.0f, 420.0f), 945.0f);
            // one rcp serves 4 divisions
            float p01 = d0 * d1, p23 = d2 * d3;
            float r = frcp(p01 * p23);
            float r01 = r * p23, r23 = r * p01;
            float h0 = n0 * (r01 * d1);
            float h1 = n1 * (r01 * d0);
            float h2 = n2 * (r23 * d3);
            float h3 = n3 * (r23 * d2);
            a0 = fmaf(h0, hsel(wah[2*g], 0), a0);
            a1 = fmaf(h0, hsel(wbh[2*g], 0), a1);
            a0 = fmaf(h1, hsel(wah[2*g], 1), a0);
            a1 = fmaf(h1, hsel(wbh[2*g], 1), a1);
            a0 = fmaf(h2, hsel(wah[2*g+1], 0), a0);
            a1 = fmaf(h2, hsel(wbh[2*g+1], 0), a1);
            a0 = fmaf(h3, hsel(wah[2*g+1], 1), a0);
            a1 = fmaf(h3, hsel(wbh[2*g+1], 1), a1);
        }
        a0 = quad_sum(a0);
        a1 = quad_sum(a1);
        // identical on all 4 lanes of the quad -> state stays consistent
        float drift = fmed3(a0, -5.0f, 5.0f);
        float diff = softplus_fast(a1) + 0.1f;
        x = fmaf(drift, SDE_DT, fmaf(diff * SDE_SQRT_DT, nz_cur, x));
        x = fmed3(x, -10.0f, 10.0f);
        // hz = sigmoid(TEMP*(|x|-half_b)) = 1/(1+exp2(Hh - CT*|x|))
        float e = fexp2(fmaf(fabsf(x), -CT, Hh));
        float hz = fminf(frcp(1.0f + e), 0.99f);
        float cross = surv * hz;
        surv = surv * (1.0f - hz);
        t += SDE_DT;                    // t is now (k+1)*DT
        ert = fmaf(cross, t, ert);
        ecorr += (x > 0.0f) ? cross : 0.0f;
        nz_cur = nz_nxt;
    }

    ert += surv;                    // * (STEPS*DT) = 1.0
    ecorr = fmaf(surv, 0.5f, ecorr);
    float rt = ert + ndt;           // seconds; x1000 applied after stats

    // --- stats over 16 sims (mask quad-redundant copies to q==0) ---
    float sr = (q == 0) ? rt : 0.0f;
    float scr = (q == 0) ? ecorr : 0.0f;
    #pragma unroll
    for (int off = 32; off > 0; off >>= 1) {
        sr += __shfl_xor(sr, off, 64);
        scr += __shfl_xor(scr, off, 64);
    }
    float mean = sr * (1.0f / 16.0f);
    float d = rt - mean;
    float vv = (q == 0) ? d * d : 0.0f;
    #pragma unroll
    for (int off = 32; off > 0; off >>= 1) vv += __shfl_xor(vv, off, 64);

    if (lane == 0) {
        float std_ms = sqrtf(vv * (1.0f / 15.0f)) * 1000.0f + 0.001f;
        float o0 = fmaf(mean * 1000.0f, osc[0], obias[0]);
        float o1 = fmaf(std_ms, osc[1], obias[1]);
        float o2 = fmaf(scr * (1.0f / 16.0f), osc[2], obias[2]);
        out[b * 3 + 0] = fixnum(o0);
        out[b * 3 + 1] = fixnum(o1);
        out[b * 3 + 2] = fixnum(o2);
    }
}

extern "C" void kernel_launch(void* const* d_in, const int* in_sizes, int n_in,
                              void* d_out, int out_size, void* d_ws, size_t ws_size,
                              hipStream_t stream) {
    const float* z     = (const float*)d_in[0];
    const float* W1    = (const float*)d_in[1];
    const float* b1    = (const float*)d_in[2];
    const float* W2    = (const float*)d_in[3];
    const float* b2    = (const float*)d_in[4];
    const float* Wb    = (const float*)d_in[5];
    const float* bb    = (const float*)d_in[6];
    const float* Wn    = (const float*)d_in[7];
    const float* bn    = (const float*)d_in[8];
    const float* osc   = (const float*)d_in[9];
    const float* obias = (const float*)d_in[10];
    const float* noise = (const float*)d_in[11];
    float* out = (float*)d_out;

    dim3 grid(SDE_B / 4), block(256);
    sde_kernel<<<grid, block, 0, stream>>>(z, W1, b1, W2, b2, Wb, bb, Wn, bn,
                                           osc, obias, noise, out);
}

// Round 8
// 346.277 us; speedup vs baseline: 1.1952x; 1.1952x over previous
//
#include <hip/hip_runtime.h>
#include <hip/hip_fp16.h>
#include <math.h>

#define SDE_B 16384
#define SDE_S 16
#define SDE_STEPS 50
#define SDE_L 128
#define SDE_DT 0.02f
#define SDE_SQRT_DT 0.14142135623730951f
#define SDE_TEMP 20.0f
#define LOG2E 1.44269504088896340736f
#define LN2 0.69314718055994530942f
#define SC2 (2.0f * LOG2E)          /* pre-scale so tanh arg feeds exp2 directly */
#define CT (SDE_TEMP * LOG2E)       /* hazard arg scale */

#if __has_builtin(__builtin_amdgcn_exp2f)
__device__ __forceinline__ float fexp2(float x) { return __builtin_amdgcn_exp2f(x); }
#else
__device__ __forceinline__ float fexp2(float x) { return __exp2f(x); }
#endif

#if __has_builtin(__builtin_amdgcn_logf)
__device__ __forceinline__ float flog2(float x) { return __builtin_amdgcn_logf(x); }
#else
__device__ __forceinline__ float flog2(float x) { return __log2f(x); }
#endif

#if __has_builtin(__builtin_amdgcn_rcpf)
__device__ __forceinline__ float frcp(float x) { return __builtin_amdgcn_rcpf(x); }
#else
__device__ __forceinline__ float frcp(float x) { return 1.0f / x; }
#endif

#if __has_builtin(__builtin_amdgcn_fmed3f)
__device__ __forceinline__ float fmed3(float x, float lo, float hi) {
    return __builtin_amdgcn_fmed3f(x, lo, hi);
}
#else
__device__ __forceinline__ float fmed3(float x, float lo, float hi) {
    return fminf(fmaxf(x, lo), hi);
}
#endif

// wave-uniform float -> SGPR
__device__ __forceinline__ float uni(float v) {
#if __has_builtin(__builtin_amdgcn_readfirstlane)
    return __int_as_float(__builtin_amdgcn_readfirstlane(__float_as_int(v)));
#else
    return v;
#endif
}

// extract one f16 from a half2 as float; constant `hi` folds; feeding fmaf()
// lets clang form v_fma_mix_f32 (full-rate, no cvt inst).
__device__ __forceinline__ float hsel(__half2 h, int hi) {
    return __half2float(hi ? __high2half(h) : __low2half(h));
}

// stable softplus: max(y,0) + log(1+exp(-|y|))
__device__ __forceinline__ float softplus_fast(float y) {
    float m = fmaxf(y, 0.0f);
    float e = fexp2(-fabsf(y) * LOG2E);
    return fmaf(LN2, flog2(1.0f + e), m);
}

// sum over the 4-lane quad (lanes grouped as sim*4+q) via DPP quad_perm
__device__ __forceinline__ float quad_sum(float v) {
#if __has_builtin(__builtin_amdgcn_mov_dpp)
    int i = __float_as_int(v);
    v += __int_as_float(__builtin_amdgcn_mov_dpp(i, 0xB1, 0xF, 0xF, true)); // xor 1
    i = __float_as_int(v);
    v += __int_as_float(__builtin_amdgcn_mov_dpp(i, 0x4E, 0xF, 0xF, true)); // xor 2
    return v;
#else
    v += __shfl_xor(v, 1, 64);
    v += __shfl_xor(v, 2, 64);
    return v;
#endif
}

__device__ __forceinline__ float fixnum(float v) {
    if (isnan(v)) return 0.0f;
    if (isinf(v)) return v > 0.0f ? 3.4028234663852886e38f : -3.4028234663852886e38f;
    return v;
}

// One wave per batch element b. 64 lanes = 16 sims x 4 hidden-quarters.
// lane = s*4 + q: sim s, hidden units j = 4*i + q, i in [0,16).
// R6 inner (exp-form tanh: trans are ~issue-cost on gfx950 per R6/R7 A/B;
// Pade regressed +78us) + R7 register diet (SGPR uniforms, saddr noise,
// med3) to get under the 64-VGPR boundary -> 8 waves/SIMD to hide the
// serial epilogue chain (R6 at 68 VGPRs = 4 waves/SIMD, ~320 stall
// cyc/step). tanh(p) = 1 - 2/(1+exp2(p*2log2e)): weights/zw pre-scaled,
// "1 - 2*" folded into w2' = -2*w2, sum(w2) in the accumulator base.
__global__ void __launch_bounds__(256) sde_kernel(
    const float* __restrict__ z,  const float* __restrict__ W1,
    const float* __restrict__ b1, const float* __restrict__ W2,
    const float* __restrict__ b2, const float* __restrict__ Wb,
    const float* __restrict__ bb, const float* __restrict__ Wn,
    const float* __restrict__ bn, const float* __restrict__ osc,
    const float* __restrict__ obias, const float* __restrict__ noise,
    float* __restrict__ out)
{
    const int lane = threadIdx.x & 63;
    const int wv = threadIdx.x >> 6;
    const int b = blockIdx.x * 4 + wv;
    const int s = lane >> 2;
    const int q = lane & 3;

    const float* zr = z + (size_t)b * SDE_L;

    // --- setup: lane l computes zW1 entry for hidden unit j = l ---
    float accz = b1[lane];
    {
        const float* wrow = W1 + lane * 130 + 2;
        #pragma unroll
        for (int m = 0; m < SDE_L; m += 2) {
            float2 w = *(const float2*)(wrow + m);
            accz = fmaf(zr[m], w.x, accz);
            accz = fmaf(zr[m + 1], w.y, accz);
        }
    }
    accz *= SC2;   // pre-scaled for exp2-tanh

    // --- boundary / ndt: 128-dot reduced over the wave ---
    float zb0 = zr[2 * lane], zb1 = zr[2 * lane + 1];
    float pb = fmaf(zb0, Wb[2 * lane], zb1 * Wb[2 * lane + 1]);
    float pn = fmaf(zb0, Wn[2 * lane], zb1 * Wn[2 * lane + 1]);
    #pragma unroll
    for (int off = 32; off > 0; off >>= 1) {
        pb += __shfl_xor(pb, off, 64);
        pn += __shfl_xor(pn, off, 64);
    }
    // wave-uniform scalars -> SGPRs
    const float Hh = uni(CT * (0.5f * (softplus_fast(pb + bb[0]) + 0.3f)));
    const float ndt = uni(softplus_fast(pn + bn[0]) + 0.05f);

    // --- pack this lane's 16 hidden units (j = 4i+q) as f16 half2 pairs ---
    __half2 zwh[8], wxh[8], wth[8], wah[8], wbh[8];
    float S2a = 0.0f, S2b = 0.0f;
    #pragma unroll
    for (int p = 0; p < 8; ++p) {
        int j0 = 4 * (2 * p) + q, j1 = 4 * (2 * p + 1) + q;
        float zw0 = __shfl(accz, j0, 64), zw1 = __shfl(accz, j1, 64);
        zwh[p] = __halves2half2(__float2half_rn(zw0), __float2half_rn(zw1));
        float2 wa0 = *(const float2*)(W1 + j0 * 130);  // {w1x, w1t}
        float2 wa1 = *(const float2*)(W1 + j1 * 130);
        wxh[p] = __halves2half2(__float2half_rn(wa0.x * SC2), __float2half_rn(wa1.x * SC2));
        wth[p] = __halves2half2(__float2half_rn(wa0.y * SC2), __float2half_rn(wa1.y * SC2));
        float a0w = W2[j0], a1w = W2[j1];
        float b0w = W2[64 + j0], b1w = W2[64 + j1];
        S2a += a0w + a1w;
        S2b += b0w + b1w;
        wah[p] = __halves2half2(__float2half_rn(-2.0f * a0w), __float2half_rn(-2.0f * a1w));
        wbh[p] = __halves2half2(__float2half_rn(-2.0f * b0w), __float2half_rn(-2.0f * b1w));
    }
    // per-lane accumulator bases: quad-sum over 4 lanes yields b2 + full sums
    const float a0base = fmaf(0.25f, b2[0], S2a);
    const float a1base = fmaf(0.25f, b2[1], S2b);

    // noise addressing: scalar k*B*S advance + 32-bit lane offset
    const int noff = b * SDE_S + s;

    float x = 0.0f, surv = 1.0f, ert = 0.0f, ecorr = 0.0f;
    float t = 0.0f;
    float nz_cur = noise[noff];   // k=0 preload

    for (int k = 0; k < SDE_STEPS; ++k) {
        // prefetch k+1 (consumed next iteration: full iteration of latency cover)
        int kn = (k + 1 < SDE_STEPS) ? k + 1 : k;
        float nz_nxt = noise[(size_t)kn * (SDE_B * SDE_S) + noff];

        float a0 = a0base, a1 = a1base;
        #pragma unroll
        for (int g = 0; g < 4; ++g) {
            // 4 units: pairs p = 2g (lo,hi), 2g+1 (lo,hi)
            float pr0 = fmaf(x, hsel(wxh[2*g], 0), fmaf(t, hsel(wth[2*g], 0), hsel(zwh[2*g], 0)));
            float pr1 = fmaf(x, hsel(wxh[2*g], 1), fmaf(t, hsel(wth[2*g], 1), hsel(zwh[2*g], 1)));
            float pr2 = fmaf(x, hsel(wxh[2*g+1], 0), fmaf(t, hsel(wth[2*g+1], 0), hsel(zwh[2*g+1], 0)));
            float pr3 = fmaf(x, hsel(wxh[2*g+1], 1), fmaf(t, hsel(wth[2*g+1], 1), hsel(zwh[2*g+1], 1)));
            float d0 = fexp2(pr0) + 1.0f;
            float d1 = fexp2(pr1) + 1.0f;
            float d2 = fexp2(pr2) + 1.0f;
            float d3 = fexp2(pr3) + 1.0f;
            // one rcp serves 4 reciprocals: g_i = 1/d_i
            float p01 = d0 * d1, p23 = d2 * d3;
            float r = frcp(p01 * p23);
            float r01 = r * p23, r23 = r * p01;
            float g0 = r01 * d1, g1 = r01 * d0;
            float g2 = r23 * d3, g3 = r23 * d2;
            // h_i = 1 - 2*g_i folded: a += g_i * (-2*w2); base carries sum(w2)
            a0 = fmaf(g0, hsel(wah[2*g], 0), a0);
            a1 = fmaf(g0, hsel(wbh[2*g], 0), a1);
            a0 = fmaf(g1, hsel(wah[2*g], 1), a0);
            a1 = fmaf(g1, hsel(wbh[2*g], 1), a1);
            a0 = fmaf(g2, hsel(wah[2*g+1], 0), a0);
            a1 = fmaf(g2, hsel(wbh[2*g+1], 0), a1);
            a0 = fmaf(g3, hsel(wah[2*g+1], 1), a0);
            a1 = fmaf(g3, hsel(wbh[2*g+1], 1), a1);
        }
        a0 = quad_sum(a0);
        a1 = quad_sum(a1);
        // identical on all 4 lanes of the quad -> state stays consistent
        float drift = fmed3(a0, -5.0f, 5.0f);
        float diff = softplus_fast(a1) + 0.1f;
        x = fmaf(drift, SDE_DT, fmaf(diff * SDE_SQRT_DT, nz_cur, x));
        x = fmed3(x, -10.0f, 10.0f);
        // hz = sigmoid(TEMP*(|x|-half_b)) = 1/(1+exp2(Hh - CT*|x|))
        float e = fexp2(fmaf(fabsf(x), -CT, Hh));
        float hz = fminf(frcp(1.0f + e), 0.99f);
        float cross = surv * hz;
        surv = surv * (1.0f - hz);
        t += SDE_DT;                    // t is now (k+1)*DT
        ert = fmaf(cross, t, ert);
        ecorr += (x > 0.0f) ? cross : 0.0f;
        nz_cur = nz_nxt;
    }

    ert += surv;                    // * (STEPS*DT) = 1.0
    ecorr = fmaf(surv, 0.5f, ecorr);
    float rt = ert + ndt;           // seconds; x1000 applied after stats

    // --- stats over 16 sims (mask quad-redundant copies to q==0) ---
    float sr = (q == 0) ? rt : 0.0f;
    float scr = (q == 0) ? ecorr : 0.0f;
    #pragma unroll
    for (int off = 32; off > 0; off >>= 1) {
        sr += __shfl_xor(sr, off, 64);
        scr += __shfl_xor(scr, off, 64);
    }
    float mean = sr * (1.0f / 16.0f);
    float d = rt - mean;
    float vv = (q == 0) ? d * d : 0.0f;
    #pragma unroll
    for (int off = 32; off > 0; off >>= 1) vv += __shfl_xor(vv, off, 64);

    if (lane == 0) {
        float std_ms = sqrtf(vv * (1.0f / 15.0f)) * 1000.0f + 0.001f;
        float o0 = fmaf(mean * 1000.0f, osc[0], obias[0]);
        float o1 = fmaf(std_ms, osc[1], obias[1]);
        float o2 = fmaf(scr * (1.0f / 16.0f), osc[2], obias[2]);
        out[b * 3 + 0] = fixnum(o0);
        out[b * 3 + 1] = fixnum(o1);
        out[b * 3 + 2] = fixnum(o2);
    }
}

extern "C" void kernel_launch(void* const* d_in, const int* in_sizes, int n_in,
                              void* d_out, int out_size, void* d_ws, size_t ws_size,
                              hipStream_t stream) {
    const float* z     = (const float*)d_in[0];
    const float* W1    = (const float*)d_in[1];
    const float* b1    = (const float*)d_in[2];
    const float* W2    = (const float*)d_in[3];
    const float* b2    = (const float*)d_in[4];
    const float* Wb    = (const float*)d_in[5];
    const float* bb    = (const float*)d_in[6];
    const float* Wn    = (const float*)d_in[7];
    const float* bn    = (const float*)d_in[8];
    const float* osc   = (const float*)d_in[9];
    const float* obias = (const float*)d_in[10];
    const float* noise = (const float*)d_in[11];
    float* out = (float*)d_out;

    dim3 grid(SDE_B / 4), block(256);
    sde_kernel<<<grid, block, 0, stream>>>(z, W1, b1, W2, b2, Wb, bb, Wn, bn,
                                           osc, obias, noise, out);
}